// Round 8
// baseline (170.002 us; speedup 1.0000x reference)
//
#include <hip/hip_runtime.h>
#include <stdint.h>

#define N 8192
#define MAX_E (64 * N)          // 524288
#define NCHUNK (N / 64)         // 128 mask chunks per row
#define TILE 2048               // cols per block (32KB LDS)
#define CTILES (N / TILE)       // 4 col-tiles
#define CPAIRS (TILE / 128)     // 16 chunk-pairs per tile
#define ROWS_PER_WAVE 8
#define WAVES 4
#define ROWS_PER_BLOCK (ROWS_PER_WAVE * WAVES)  // 32
#define RGROUPS (N / ROWS_PER_BLOCK)            // 256
#define TOTAL_BLOCKS (RGROUPS * CTILES)         // 1024
// d_ws is poisoned to 0xAA before every timed launch -> the done counter
// starts at 0xAAAAAAAA; the 1024th arriving block sees old == POISON+1023.
// If a run ever starts unpoisoned, no block is "last" and offsets keep their
// previous (identical, correct) values -> still correct.
#define DONE_POISON 0xAAAAAAAAu

// Exact replication of numpy f32: sum(pos*pos, -1) = ((x*x)+(y*y))+(z*z),
// each product rounded (no fma).
__device__ __forceinline__ float sq_exact(float x, float y, float z) {
    return __fadd_rn(__fadd_rn(__fmul_rn(x, x), __fmul_rn(y, y)), __fmul_rn(z, z));
}

// d2 = RN(sqsum - RN(2*dot)); 2*dot is exact so fma(-2,dot,sqsum) is bit-identical.
// dist<5 <=> d2 < 0x1.8ffffep+4f (largest f32 below 25 has correctly-rounded sqrt
// equal to exactly 5.0, so that value must be excluded).
__device__ __forceinline__ bool edge_pred(float xi, float yi, float zi, float sqi,
                                          const float4& pj) {
    float dot = __fmaf_rn(zi, pj.z, __fmaf_rn(yi, pj.y, __fmul_rn(xi, pj.x)));
    float d2  = __fmaf_rn(-2.0f, dot, __fadd_rn(sqi, pj.w));
    return d2 < 0x1.8ffffep+4f;
}

// Pass 1: grid (row-group, col-tile). Each wave: 8 rows x 2048 cols.
// Ballot masks kept in owner-lane registers (lanes 0..15 hold this tile's 16
// chunk-pairs), flushed once. The LAST block to finish (device-scope atomic)
// also performs the row-count scan -> offsets (fused; saves a launch).
__global__ __launch_bounds__(256) void mask_kernel(const float* __restrict__ posf,
                                                   uint64_t* __restrict__ masks,
                                                   int* __restrict__ counts4,
                                                   int* __restrict__ offsets,
                                                   unsigned int* __restrict__ done) {
    __shared__ float4 pts[TILE];
    const int tid  = threadIdx.x;
    const int wave = tid >> 6;
    const int lane = tid & 63;
    const int row0 = blockIdx.x * ROWS_PER_BLOCK + wave * ROWS_PER_WAVE;
    const int ct   = blockIdx.y;          // col tile
    const int cb   = ct * TILE;           // col base

    float xi[ROWS_PER_WAVE], yi[ROWS_PER_WAVE], zi[ROWS_PER_WAVE], sqi[ROWS_PER_WAVE];
    uint64_t k0[ROWS_PER_WAVE], k1[ROWS_PER_WAVE];
#pragma unroll
    for (int r = 0; r < ROWS_PER_WAVE; r++) {
        int i = row0 + r;
        xi[r] = posf[3 * i + 0];
        yi[r] = posf[3 * i + 1];
        zi[r] = posf[3 * i + 2];
        sqi[r] = sq_exact(xi[r], yi[r], zi[r]);
        k0[r] = 0; k1[r] = 0;
    }

    for (int k = tid; k < TILE; k += 256) {
        float x = posf[3 * (cb + k) + 0];
        float y = posf[3 * (cb + k) + 1];
        float z = posf[3 * (cb + k) + 2];
        pts[k] = make_float4(x, y, z, sq_exact(x, y, z));
    }
    __syncthreads();

    float4 pa = pts[lane];
    float4 pb = pts[64 + lane];
#pragma unroll
    for (int c = 0; c < TILE; c += 128) {
        // prefetch next chunk-pair (masked index: always in-bounds, no branch)
        float4 na = pts[((c + 128) & (TILE - 1)) + lane];
        float4 nb = pts[((c + 192) & (TILE - 1)) + lane];
        const int owner = c >> 7;         // 0..15, wave-uniform
#pragma unroll
        for (int r = 0; r < ROWS_PER_WAVE; r++) {
            uint64_t ma = __ballot(edge_pred(xi[r], yi[r], zi[r], sqi[r], pa));
            if (lane == owner) k0[r] = ma;
            uint64_t mb = __ballot(edge_pred(xi[r], yi[r], zi[r], sqi[r], pb));
            if (lane == owner) k1[r] = mb;
        }
        pa = na; pb = nb;
    }

#pragma unroll
    for (int r = 0; r < ROWS_PER_WAVE; r++) {
        const int row = row0 + r;
        // clear the self bit if this tile contains column `row`
        if ((row >> 11) == ct) {
            const int ls = (row & (TILE - 1)) >> 6;   // local chunk 0..31
            if (lane == (ls >> 1)) {
                uint64_t clr = ~(1ull << (row & 63));
                if (ls & 1) k1[r] &= clr; else k0[r] &= clr;
            }
        }
        if (lane < CPAIRS) {   // lanes 0..15 hold this tile's chunk-pairs
            ulonglong2 v; v.x = k0[r]; v.y = k1[r];
            ((ulonglong2*)(masks + (size_t)row * NCHUNK))[ct * CPAIRS + lane] = v;
        }
        int t = __popcll(k0[r]) + __popcll(k1[r]);
#pragma unroll
        for (int o = 32; o > 0; o >>= 1) t += __shfl_down(t, o);
        if (lane == 0) counts4[row * CTILES + ct] = t;
    }

    // ---- fused scan: last block to finish scans counts4 -> offsets ----
    __shared__ int is_last;
    __threadfence();                       // release: counts4 visible device-wide
    if (tid == 0) {
        unsigned int old = atomicAdd(done, 1u);
        is_last = (old == DONE_POISON + (TOTAL_BLOCKS - 1)) ? 1 : 0;
    }
    __syncthreads();
    if (!is_last) return;
    __threadfence();                       // acquire: see all blocks' counts4

    __shared__ int part[256];
    int local[32];
    int s = 0;
#pragma unroll
    for (int k = 0; k < 32; k++) {
        int v = 0;
#pragma unroll
        for (int j = 0; j < CTILES; j++) v += counts4[(tid * 32 + k) * CTILES + j];
        local[k] = v; s += v;
    }
    part[tid] = s;
    __syncthreads();
    for (int off = 1; off < 256; off <<= 1) {
        int v = (tid >= off) ? part[tid - off] : 0;
        __syncthreads();
        part[tid] += v;
        __syncthreads();
    }
    int run = (tid > 0) ? part[tid - 1] : 0;  // exclusive base
#pragma unroll
    for (int k = 0; k < 32; k++) { offsets[tid * 32 + k] = run; run += local[k]; }
    if (tid == 255) offsets[N] = part[255];   // total edge count
}

// Pass 2: masks -> ordered edge list + tail fill with -1.
// One wave per row; lane l holds chunks 2l,2l+1; wave-exclusive-scan of
// popcounts gives in-order slots.
__global__ __launch_bounds__(256) void emit_kernel(const uint64_t* __restrict__ masks,
                                                   const int* __restrict__ offsets,
                                                   int* __restrict__ out) {
    const int wave = threadIdx.x >> 6;
    const int lane = threadIdx.x & 63;
    const int row  = blockIdx.x * 4 + wave;

    // tail fill: slots [E, MAX_E) of both halves get -1. 524288 threads cover
    // the <=262K tail slots with one conditional store pair each.
    {
        const int E = offsets[N];
        const int idx = E + blockIdx.x * 256 + threadIdx.x;
        if (idx < MAX_E) { out[idx] = -1; out[MAX_E + idx] = -1; }
    }

    ulonglong2 v = ((const ulonglong2*)(masks + (size_t)row * NCHUNK))[lane];
    int s0 = __popcll(v.x), s1 = __popcll(v.y);
    int x = s0 + s1;
#pragma unroll
    for (int o = 1; o < 64; o <<= 1) {
        int t = __shfl_up(x, o);
        if (lane >= o) x += t;
    }
    int slot = offsets[row] + (x - (s0 + s1));  // exclusive prefix within row

    const int col0 = lane * 128;  // chunk 2*lane covers cols [128*lane, 128*lane+64)
    uint64_t m = v.x;
    while (m) {
        int b = __ffsll((unsigned long long)m) - 1;
        m &= m - 1;
        if (slot < MAX_E) { out[slot] = row; out[MAX_E + slot] = col0 + b; }
        slot++;
    }
    m = v.y;
    while (m) {
        int b = __ffsll((unsigned long long)m) - 1;
        m &= m - 1;
        if (slot < MAX_E) { out[slot] = row; out[MAX_E + slot] = col0 + 64 + b; }
        slot++;
    }
}

extern "C" void kernel_launch(void* const* d_in, const int* in_sizes, int n_in,
                              void* d_out, int out_size, void* d_ws, size_t ws_size,
                              hipStream_t stream) {
    const float* posf = (const float*)d_in[0];
    int* out = (int*)d_out;
    int* counts4 = (int*)d_ws;                                       // 4*N ints = 128KB
    unsigned int* done = (unsigned int*)((char*)d_ws + (192 << 10)); // 4B (0xAA-poisoned)
    int* offsets = (int*)((char*)d_ws + (256 << 10));                // N+1 ints
    uint64_t* masks = (uint64_t*)((char*)d_ws + (512 << 10));        // 8 MB

    dim3 grid(RGROUPS, CTILES);
    mask_kernel<<<grid, 256, 0, stream>>>(posf, masks, counts4, offsets, done);
    emit_kernel<<<N / 4, 256, 0, stream>>>(masks, offsets, out);
}

// Round 9
// 91.190 us; speedup vs baseline: 1.8643x; 1.8643x over previous
//
#include <hip/hip_runtime.h>
#include <stdint.h>

#define N 8192
#define MAX_E (64 * N)          // 524288
#define NCHUNK (N / 64)         // 128 mask chunks per row
#define TILE 2048               // cols per block (32KB LDS)
#define CTILES (N / TILE)       // 4 col-tiles
#define CPAIRS (TILE / 128)     // 16 chunk-pairs per tile
#define ROWS_PER_WAVE 8
#define WAVES 4
#define ROWS_PER_BLOCK (ROWS_PER_WAVE * WAVES)  // 32
#define RGROUPS (N / ROWS_PER_BLOCK)            // 256
#define E_BLOCKS 512                             // emit blocks (16 rows each)
#define E_ROWS 16

// Exact replication of numpy f32: sum(pos*pos, -1) = ((x*x)+(y*y))+(z*z),
// each product rounded (no fma).
__device__ __forceinline__ float sq_exact(float x, float y, float z) {
    return __fadd_rn(__fadd_rn(__fmul_rn(x, x), __fmul_rn(y, y)), __fmul_rn(z, z));
}

// d2 = RN(sqsum - RN(2*dot)); 2*dot is exact so fma(-2,dot,sqsum) is bit-identical.
// dist<5 <=> d2 < 0x1.8ffffep+4f (largest f32 below 25 has correctly-rounded sqrt
// equal to exactly 5.0, so that value must be excluded).
__device__ __forceinline__ bool edge_pred(float xi, float yi, float zi, float sqi,
                                          const float4& pj) {
    float dot = __fmaf_rn(zi, pj.z, __fmaf_rn(yi, pj.y, __fmul_rn(xi, pj.x)));
    float d2  = __fmaf_rn(-2.0f, dot, __fadd_rn(sqi, pj.w));
    return d2 < 0x1.8ffffep+4f;
}

// Pass 1: grid (row-group, col-tile). Each wave: 8 rows x 2048 cols.
// Ballot masks kept in owner-lane registers (lanes 0..15 hold this tile's 16
// chunk-pairs), flushed once. NO device-scope fences (R8 lesson: threadfence
// per block = L2 flush per block on non-coherent per-XCD L2 -> 4x slowdown).
__global__ __launch_bounds__(256) void mask_kernel(const float* __restrict__ posf,
                                                   uint64_t* __restrict__ masks,
                                                   int* __restrict__ counts4) {
    __shared__ float4 pts[TILE];
    const int tid  = threadIdx.x;
    const int wave = tid >> 6;
    const int lane = tid & 63;
    const int row0 = blockIdx.x * ROWS_PER_BLOCK + wave * ROWS_PER_WAVE;
    const int ct   = blockIdx.y;          // col tile
    const int cb   = ct * TILE;           // col base

    float xi[ROWS_PER_WAVE], yi[ROWS_PER_WAVE], zi[ROWS_PER_WAVE], sqi[ROWS_PER_WAVE];
    uint64_t k0[ROWS_PER_WAVE], k1[ROWS_PER_WAVE];
#pragma unroll
    for (int r = 0; r < ROWS_PER_WAVE; r++) {
        int i = row0 + r;
        xi[r] = posf[3 * i + 0];
        yi[r] = posf[3 * i + 1];
        zi[r] = posf[3 * i + 2];
        sqi[r] = sq_exact(xi[r], yi[r], zi[r]);
        k0[r] = 0; k1[r] = 0;
    }

    for (int k = tid; k < TILE; k += 256) {
        float x = posf[3 * (cb + k) + 0];
        float y = posf[3 * (cb + k) + 1];
        float z = posf[3 * (cb + k) + 2];
        pts[k] = make_float4(x, y, z, sq_exact(x, y, z));
    }
    __syncthreads();

    float4 pa = pts[lane];
    float4 pb = pts[64 + lane];
    // unroll 4 (not 16): full unroll is ~18KB of code -> I-cache pressure.
#pragma unroll 4
    for (int c = 0; c < TILE; c += 128) {
        // prefetch next chunk-pair (masked index: always in-bounds, no branch)
        float4 na = pts[((c + 128) & (TILE - 1)) + lane];
        float4 nb = pts[((c + 192) & (TILE - 1)) + lane];
        const int owner = c >> 7;         // 0..15, wave-uniform
#pragma unroll
        for (int r = 0; r < ROWS_PER_WAVE; r++) {
            uint64_t ma = __ballot(edge_pred(xi[r], yi[r], zi[r], sqi[r], pa));
            if (lane == owner) k0[r] = ma;
            uint64_t mb = __ballot(edge_pred(xi[r], yi[r], zi[r], sqi[r], pb));
            if (lane == owner) k1[r] = mb;
        }
        pa = na; pb = nb;
    }

#pragma unroll
    for (int r = 0; r < ROWS_PER_WAVE; r++) {
        const int row = row0 + r;
        // clear the self bit if this tile contains column `row`
        if ((row >> 11) == ct) {
            const int ls = (row & (TILE - 1)) >> 6;   // local chunk 0..31
            if (lane == (ls >> 1)) {
                uint64_t clr = ~(1ull << (row & 63));
                if (ls & 1) k1[r] &= clr; else k0[r] &= clr;
            }
        }
        if (lane < CPAIRS) {   // lanes 0..15 hold this tile's chunk-pairs
            ulonglong2 v; v.x = k0[r]; v.y = k1[r];
            ((ulonglong2*)(masks + (size_t)row * NCHUNK))[ct * CPAIRS + lane] = v;
        }
        int t = __popcll(k0[r]) + __popcll(k1[r]);
#pragma unroll
        for (int o = 32; o > 0; o >>= 1) t += __shfl_down(t, o);
        if (lane == 0) counts4[row * CTILES + ct] = t;
    }
}

// Pass 2: masks -> ordered edge list + tail fill with -1.
// Each block REDUNDANTLY recomputes the row-offset scan from counts4 (32KB,
// L2-hot; no inter-block comms, no fence, one launch saved). 16 rows/block,
// 4 rows/wave; lane l holds chunks 2l,2l+1 of its row.
__global__ __launch_bounds__(256) void emit_kernel(const uint64_t* __restrict__ masks,
                                                   const int* __restrict__ counts4,
                                                   int* __restrict__ out) {
    const int tid  = threadIdx.x;
    const int wave = tid >> 6;
    const int lane = tid & 63;
    const int row0 = blockIdx.x * E_ROWS;

    __shared__ int part[256];
    __shared__ int roff[E_ROWS];
    __shared__ int Etot_s;

    // --- redundant scan: thread t sums rows [t*32, t*32+32) ---
    const int4* c4 = (const int4*)counts4;   // one int4 = one row's 4 partials
    int s = 0;
#pragma unroll 8
    for (int k = 0; k < 32; k++) {
        int4 v = c4[tid * 32 + k];
        s += v.x + v.y + v.z + v.w;
    }
    part[tid] = s;
    __syncthreads();
    for (int off = 1; off < 256; off <<= 1) {
        int v = (tid >= off) ? part[tid - off] : 0;
        __syncthreads();
        part[tid] += v;
        __syncthreads();
    }
    // offsets for this block's 16 rows: rows live in 32-row chunk ch = row0>>5
    if (tid < E_ROWS) {
        const int ch = row0 >> 5;
        int off = (ch > 0) ? part[ch - 1] : 0;   // exclusive prefix of chunk
        for (int rr = (ch << 5); rr < row0 + tid; rr++) {
            int4 v = c4[rr];
            off += v.x + v.y + v.z + v.w;
        }
        roff[tid] = off;
    }
    if (tid == 0) Etot_s = part[255];
    __syncthreads();

    // --- tail fill: slots [E, MAX_E) of both halves get -1 ---
    const int E = Etot_s;
    for (int idx = E + blockIdx.x * 256 + tid; idx < MAX_E; idx += E_BLOCKS * 256) {
        out[idx] = -1; out[MAX_E + idx] = -1;
    }

    // --- extract: 4 rows per wave ---
#pragma unroll
    for (int r = 0; r < 4; r++) {
        const int lr  = wave * 4 + r;        // 0..15
        const int row = row0 + lr;
        ulonglong2 v = ((const ulonglong2*)(masks + (size_t)row * NCHUNK))[lane];
        int s0 = __popcll(v.x), s1 = __popcll(v.y);
        int x = s0 + s1;
#pragma unroll
        for (int o = 1; o < 64; o <<= 1) {
            int t = __shfl_up(x, o);
            if (lane >= o) x += t;
        }
        int slot = roff[lr] + (x - (s0 + s1));  // exclusive prefix within row

        const int col0 = lane * 128;  // chunk 2*lane covers cols [128*lane, +64)
        uint64_t m = v.x;
        while (m) {
            int b = __ffsll((unsigned long long)m) - 1;
            m &= m - 1;
            if (slot < MAX_E) { out[slot] = row; out[MAX_E + slot] = col0 + b; }
            slot++;
        }
        m = v.y;
        while (m) {
            int b = __ffsll((unsigned long long)m) - 1;
            m &= m - 1;
            if (slot < MAX_E) { out[slot] = row; out[MAX_E + slot] = col0 + 64 + b; }
            slot++;
        }
    }
}

extern "C" void kernel_launch(void* const* d_in, const int* in_sizes, int n_in,
                              void* d_out, int out_size, void* d_ws, size_t ws_size,
                              hipStream_t stream) {
    const float* posf = (const float*)d_in[0];
    int* out = (int*)d_out;
    int* counts4 = (int*)d_ws;                                   // 4*N ints = 128KB
    uint64_t* masks = (uint64_t*)((char*)d_ws + (512 << 10));    // 8 MB

    dim3 grid(RGROUPS, CTILES);
    mask_kernel<<<grid, 256, 0, stream>>>(posf, masks, counts4);
    emit_kernel<<<E_BLOCKS, 256, 0, stream>>>(masks, counts4, out);
}